// Round 1
// baseline (1455.620 us; speedup 1.0000x reference)
//
#include <hip/hip_runtime.h>

// SAGEEncoder: 5x fused SAGEConv(max|mean cat -> lin_l + lin_r) + LN + residual + SiLU,
// then MLP head (Linear->SiLU->LN->Linear). fp32 throughout.
// Structure: CSR build once; per-layer fused kernel (wave=node-group, lane=feature);
// weights LDS-staged transposed; GEMMs via readlane(SGPR k) + fmac.

#define NPW 8  // nodes per wave

__device__ __forceinline__ float rl_f(float v, int k) {
  return __int_as_float(__builtin_amdgcn_readlane(__float_as_int(v), k));
}

// ---- edge dtype detection: int64 iff the first 32 odd u32 slots are all zero ----
__global__ void detect_idx64(const unsigned* __restrict__ e, int* __restrict__ flag) {
  if (threadIdx.x == 0 && blockIdx.x == 0) {
    int is64 = 1;
    for (int i = 0; i < 32; ++i)
      if (e[2 * i + 1] != 0u) { is64 = 0; break; }
    *flag = is64;
  }
}

__device__ __forceinline__ int edge_val(const void* e, int is64, long long idx) {
  if (is64) return (int)((const long long*)e)[idx];
  return ((const int*)e)[idx];
}

__global__ void count_deg(const void* __restrict__ edges, const int* __restrict__ flag,
                          int* __restrict__ deg, int nE) {
  int is64 = *flag;
  long long E = nE;
  for (int i = blockIdx.x * blockDim.x + threadIdx.x; i < nE; i += gridDim.x * blockDim.x) {
    int dst = edge_val(edges, is64, E + i);
    atomicAdd(&deg[dst], 1);
  }
}

// single-block 2-pass exclusive scan over n (<=1024*chunk) elements
__global__ void scan_deg(const int* __restrict__ deg, int* __restrict__ row_start, int n) {
  __shared__ int sums[1024];
  int t = threadIdx.x;
  int chunk = (n + 1023) >> 10;
  int lo = t * chunk;
  int hi = min(lo + chunk, n);
  int s = 0;
  for (int i = lo; i < hi; ++i) s += deg[i];
  sums[t] = s;
  __syncthreads();
  for (int off = 1; off < 1024; off <<= 1) {
    int v = (t >= off) ? sums[t - off] : 0;
    __syncthreads();
    sums[t] += v;
    __syncthreads();
  }
  int run = (t > 0) ? sums[t - 1] : 0;
  for (int i = lo; i < hi; ++i) { row_start[i] = run; run += deg[i]; }
  if (t == 1023) row_start[n] = sums[1023];
}

__global__ void fill_csr(const void* __restrict__ edges, const int* __restrict__ flag,
                         const int* __restrict__ row_start, int* __restrict__ cursor,
                         int* __restrict__ csr_src, int nE) {
  int is64 = *flag;
  long long E = nE;
  for (int i = blockIdx.x * blockDim.x + threadIdx.x; i < nE; i += gridDim.x * blockDim.x) {
    int src = edge_val(edges, is64, i);
    int dst = edge_val(edges, is64, E + i);
    int p = atomicAdd(&cursor[dst], 1);
    csr_src[row_start[dst] + p] = src;
  }
}

// ---- fused SAGE layer: conv -> LN -> +residual -> SiLU ----
// lane = output feature (64), wave handles NPW nodes.
template <bool FIRST>
__global__ __launch_bounds__(256) void sage_layer(
    const float* __restrict__ in, float* __restrict__ out,
    const int* __restrict__ row_start, const int* __restrict__ csr_src,
    const float* __restrict__ wl,  // [64,128]
    const float* __restrict__ bl,  // [64]
    const float* __restrict__ wr,  // [64,64]
    const float* __restrict__ lng, const float* __restrict__ lnb,
    const float* __restrict__ aw,  // adapter [64,64] (FIRST only)
    const float* __restrict__ ab,  // adapter bias (FIRST only)
    int nN) {
  __shared__ float wl_t[128][65];            // wl_t[k][f] = wl[f][k]
  __shared__ float wr_t[64][65];             // wr_t[k][f] = wr[f][k]
  __shared__ float ad_t[FIRST ? 64 : 1][65]; // ad_t[k][f] = aw[f][k]

  int t = threadIdx.x;
  for (int i = t; i < 64 * 128; i += 256) {
    int f = i >> 7, k = i & 127;
    wl_t[k][f] = wl[i];
  }
  for (int i = t; i < 64 * 64; i += 256) {
    int f = i >> 6, k = i & 63;
    wr_t[k][f] = wr[i];
    if (FIRST) ad_t[k][f] = aw[i];
  }
  __syncthreads();

  int wv = t >> 6, lane = t & 63;
  float blf = bl[lane], gf = lng[lane], bf = lnb[lane];
  float abf = FIRST ? ab[lane] : 0.f;

  int base0 = (blockIdx.x * 4 + wv) * NPW;
  int stride = gridDim.x * 4 * NPW;

  for (int base = base0; base < nN; base += stride) {
    float amax[NPW], amean[NPW], xr[NPW], acc[NPW], accr[NPW];
#pragma unroll
    for (int j = 0; j < NPW; ++j) {
      int nj = base + j;
      bool ok = nj < nN;
      int e0 = ok ? row_start[nj] : 0;
      int e1 = ok ? row_start[nj + 1] : 0;
      float mx = -3.402823466e38f, sm = 0.f;
      int e = e0;
      for (; e + 3 < e1; e += 4) {
        int s0 = csr_src[e], s1 = csr_src[e + 1], s2 = csr_src[e + 2], s3 = csr_src[e + 3];
        float v0 = in[(size_t)s0 * 64 + lane];
        float v1 = in[(size_t)s1 * 64 + lane];
        float v2 = in[(size_t)s2 * 64 + lane];
        float v3 = in[(size_t)s3 * 64 + lane];
        mx = fmaxf(fmaxf(mx, v0), fmaxf(fmaxf(v1, v2), v3));
        sm += (v0 + v1) + (v2 + v3);
      }
      for (; e < e1; ++e) {
        int s = csr_src[e];
        float v = in[(size_t)s * 64 + lane];
        mx = fmaxf(mx, v);
        sm += v;
      }
      int dg = e1 - e0;
      amax[j] = dg > 0 ? mx : 0.f;
      amean[j] = sm / fmaxf((float)dg, 1.f);
      xr[j] = ok ? in[(size_t)nj * 64 + lane] : 0.f;
      acc[j] = blf;
      accr[j] = abf;
    }

    // GEMM: acc[f] = bl[f] + sum_k amax[k]*wl[f][k] + amean[k]*wl[f][64+k] + x[k]*wr[f][k]
    for (int k = 0; k < 64; ++k) {
      float w0 = wl_t[k][lane];
      float w1 = wl_t[64 + k][lane];
      float w2 = wr_t[k][lane];
      float w3 = FIRST ? ad_t[FIRST ? k : 0][lane] : 0.f;
#pragma unroll
      for (int j = 0; j < NPW; ++j) {
        acc[j] = fmaf(rl_f(amax[j], k), w0, acc[j]);
        acc[j] = fmaf(rl_f(amean[j], k), w1, acc[j]);
        float xk = rl_f(xr[j], k);
        acc[j] = fmaf(xk, w2, acc[j]);
        if (FIRST) accr[j] = fmaf(xk, w3, accr[j]);
      }
    }

#pragma unroll
    for (int j = 0; j < NPW; ++j) {
      int nj = base + j;
      float a = acc[j];
      float s1 = a, s2 = a * a;
#pragma unroll
      for (int off = 32; off >= 1; off >>= 1) {
        s1 += __shfl_xor(s1, off);
        s2 += __shfl_xor(s2, off);
      }
      float mean = s1 * 0.015625f;
      float var = s2 * 0.015625f - mean * mean;
      float res = FIRST ? accr[j] : xr[j];
      float y = (a - mean) * rsqrtf(var + 1e-5f) * gf + bf + res;
      float h = y / (1.f + __expf(-y));
      if (nj < nN) out[(size_t)nj * 64 + lane] = h;
    }
  }
}

// ---- MLP head: silu(h@w1.T+b1) -> LN -> @w2.T+b2 ----
__global__ __launch_bounds__(256) void mlp_head(
    const float* __restrict__ in, float* __restrict__ out,
    const float* __restrict__ w1,   // [256,64]
    const float* __restrict__ b1,   // [256]
    const float* __restrict__ lng, const float* __restrict__ lnb,  // [256]
    const float* __restrict__ w2,   // [64,256]
    const float* __restrict__ b2,   // [64]
    int nN) {
  __shared__ float w1_t[64][257];   // w1_t[k][p] = w1[p][k]
  __shared__ float w2_t[256][65];   // w2_t[p][f] = w2[f][p]
  int t = threadIdx.x;
  for (int i = t; i < 256 * 64; i += 256) {
    int p = i >> 6, k = i & 63;
    w1_t[k][p] = w1[i];
  }
  for (int i = t; i < 64 * 256; i += 256) {
    int f = i >> 8, p = i & 255;
    w2_t[p][f] = w2[i];
  }
  __syncthreads();

  int wv = t >> 6, lane = t & 63;
  float bb1[4], gg[4], bb[4];
#pragma unroll
  for (int c = 0; c < 4; ++c) {
    bb1[c] = b1[lane + 64 * c];
    gg[c] = lng[lane + 64 * c];
    bb[c] = lnb[lane + 64 * c];
  }
  float b2f = b2[lane];

  int base0 = (blockIdx.x * 4 + wv) * NPW;
  int stride = gridDim.x * 4 * NPW;

  for (int base = base0; base < nN; base += stride) {
    float h[NPW], u0[NPW], u1[NPW], u2[NPW], u3[NPW], o[NPW];
#pragma unroll
    for (int j = 0; j < NPW; ++j) {
      int nj = base + j;
      h[j] = (nj < nN) ? in[(size_t)nj * 64 + lane] : 0.f;
      u0[j] = u1[j] = u2[j] = u3[j] = 0.f;
      o[j] = b2f;
    }
    // u[p=lane+64c] = sum_k h[k] * w1[p][k]
    for (int k = 0; k < 64; ++k) {
      float a0 = w1_t[k][lane];
      float a1 = w1_t[k][lane + 64];
      float a2 = w1_t[k][lane + 128];
      float a3 = w1_t[k][lane + 192];
#pragma unroll
      for (int j = 0; j < NPW; ++j) {
        float hk = rl_f(h[j], k);
        u0[j] = fmaf(hk, a0, u0[j]);
        u1[j] = fmaf(hk, a1, u1[j]);
        u2[j] = fmaf(hk, a2, u2[j]);
        u3[j] = fmaf(hk, a3, u3[j]);
      }
    }
    // silu + LN(256)
#pragma unroll
    for (int j = 0; j < NPW; ++j) {
      float v0 = u0[j] + bb1[0]; v0 = v0 / (1.f + __expf(-v0));
      float v1 = u1[j] + bb1[1]; v1 = v1 / (1.f + __expf(-v1));
      float v2 = u2[j] + bb1[2]; v2 = v2 / (1.f + __expf(-v2));
      float v3 = u3[j] + bb1[3]; v3 = v3 / (1.f + __expf(-v3));
      float s1 = (v0 + v1) + (v2 + v3);
      float s2 = (v0 * v0 + v1 * v1) + (v2 * v2 + v3 * v3);
#pragma unroll
      for (int off = 32; off >= 1; off >>= 1) {
        s1 += __shfl_xor(s1, off);
        s2 += __shfl_xor(s2, off);
      }
      float mean = s1 * 0.00390625f;
      float var = s2 * 0.00390625f - mean * mean;
      float rs = rsqrtf(var + 1e-5f);
      u0[j] = (v0 - mean) * rs * gg[0] + bb[0];
      u1[j] = (v1 - mean) * rs * gg[1] + bb[1];
      u2[j] = (v2 - mean) * rs * gg[2] + bb[2];
      u3[j] = (v3 - mean) * rs * gg[3] + bb[3];
    }
    // out[f=lane] = b2[f] + sum_{c,k} un[c*64+k] * w2[f][c*64+k]
    for (int k = 0; k < 64; ++k) {
      float c0 = w2_t[k][lane];
      float c1 = w2_t[64 + k][lane];
      float c2 = w2_t[128 + k][lane];
      float c3 = w2_t[192 + k][lane];
#pragma unroll
      for (int j = 0; j < NPW; ++j) {
        o[j] = fmaf(rl_f(u0[j], k), c0, o[j]);
        o[j] = fmaf(rl_f(u1[j], k), c1, o[j]);
        o[j] = fmaf(rl_f(u2[j], k), c2, o[j]);
        o[j] = fmaf(rl_f(u3[j], k), c3, o[j]);
      }
    }
#pragma unroll
    for (int j = 0; j < NPW; ++j) {
      int nj = base + j;
      if (nj < nN) out[(size_t)nj * 64 + lane] = o[j];
    }
  }
}

extern "C" void kernel_launch(void* const* d_in, const int* in_sizes, int n_in,
                              void* d_out, int out_size, void* d_ws, size_t ws_size,
                              hipStream_t stream) {
  const float* x = (const float*)d_in[0];
  const void* edges = d_in[1];
  const float* conv_wl = (const float*)d_in[2];
  const float* conv_bl = (const float*)d_in[3];
  const float* conv_wr = (const float*)d_in[4];
  const float* ln_g = (const float*)d_in[5];
  const float* ln_b = (const float*)d_in[6];
  const float* adapter_w = (const float*)d_in[7];
  const float* adapter_b = (const float*)d_in[8];
  const float* mlp_w1 = (const float*)d_in[9];
  const float* mlp_b1 = (const float*)d_in[10];
  const float* mlp_lng = (const float*)d_in[11];
  const float* mlp_lnb = (const float*)d_in[12];
  const float* mlp_w2 = (const float*)d_in[13];
  const float* mlp_b2 = (const float*)d_in[14];

  const int N = in_sizes[0] / 64;
  const int E = in_sizes[1] / 2;
  const int NL = in_sizes[2] / (64 * 128);  // 5

  // workspace layout (ints, 64-element aligned blocks)
  int* deg = (int*)d_ws;
  int* cursor = deg + ((N + 63) & ~63);
  int* row_start = cursor + ((N + 63) & ~63);
  int* csr_src = row_start + ((N + 1 + 63) & ~63);
  int* flag = csr_src + ((E + 63) & ~63);
  float* h_ws = (float*)(flag + 64);
  float* outf = (float*)d_out;

  hipMemsetAsync(deg, 0, (size_t)N * 4, stream);
  hipMemsetAsync(cursor, 0, (size_t)N * 4, stream);

  detect_idx64<<<1, 64, 0, stream>>>((const unsigned*)edges, flag);
  count_deg<<<2048, 256, 0, stream>>>(edges, flag, deg, E);
  scan_deg<<<1, 1024, 0, stream>>>(deg, row_start, N);
  fill_csr<<<2048, 256, 0, stream>>>(edges, flag, row_start, cursor, csr_src, E);

  // layer i: src alternates so that the last layer lands in h_ws; MLP -> d_out.
  const float* src = x;
  for (int i = 0; i < NL; ++i) {
    float* dst = (((NL - i) & 1) == 1) ? h_ws : outf;
    const float* wl = conv_wl + (size_t)i * 64 * 128;
    const float* bl = conv_bl + (size_t)i * 64;
    const float* wr = conv_wr + (size_t)i * 64 * 64;
    const float* g = ln_g + (size_t)i * 64;
    const float* b = ln_b + (size_t)i * 64;
    if (i == 0) {
      sage_layer<true><<<512, 256, 0, stream>>>(src, dst, row_start, csr_src, wl, bl, wr,
                                                g, b, adapter_w, adapter_b, N);
    } else {
      sage_layer<false><<<768, 256, 0, stream>>>(src, dst, row_start, csr_src, wl, bl, wr,
                                                 g, b, adapter_w, adapter_b, N);
    }
    src = dst;
  }
  mlp_head<<<256, 256, 0, stream>>>(src, outf, mlp_w1, mlp_b1, mlp_lng, mlp_lnb,
                                    mlp_w2, mlp_b2, N);
}